// Round 1
// baseline (711.056 us; speedup 1.0000x reference)
//
#include <hip/hip_runtime.h>

// PointPillars pseudo-image: scatter (N=B*12000, C=64) features into
// (B=16, C=64, 400, 400) canvas. Inverted to a gather so the 655 MB output
// is written exactly once with coalesced float4 stores.

constexpr int BATCH = 16;
constexpr int CH    = 64;
constexpr int NYD   = 400;
constexpr int NXD   = 400;
constexpr int NYNX  = NYD * NXD;   // 160000 cells per batch

// Phase 1: map[b*NYNX + y*NX + x] = voxel index i  (map pre-filled with -1)
__global__ void scatter_map_kernel(const int4* __restrict__ idx,
                                   int* __restrict__ map, int n) {
    int i = blockIdx.x * blockDim.x + threadIdx.x;
    if (i < n) {
        int4 v = idx[i];             // fields: b, z, y, x
        map[v.x * NYNX + v.z * NXD + v.w] = i;
    }
}

// Phase 2: out[b, c, y, x] = (map[b,y,x] >= 0) ? feat[map*CH + c] : 0
// One thread handles 4 adjacent cells (x-contiguous) -> float4 stores.
__global__ void gather_kernel(const float* __restrict__ feat,
                              const int* __restrict__ map,
                              float* __restrict__ out) {
    const int b     = blockIdx.y;
    const int cell4 = blockIdx.x * blockDim.x + threadIdx.x;
    if (cell4 >= NYNX / 4) return;
    const int yx = cell4 * 4;

    const int4 m = *reinterpret_cast<const int4*>(map + b * NYNX + yx);
    float* outb = out + (size_t)b * CH * NYNX + yx;
    const float4 z4 = make_float4(0.f, 0.f, 0.f, 0.f);

    for (int c = 0; c < CH; c += 4) {
        float4 fx = (m.x >= 0) ? *reinterpret_cast<const float4*>(feat + (size_t)m.x * CH + c) : z4;
        float4 fy = (m.y >= 0) ? *reinterpret_cast<const float4*>(feat + (size_t)m.y * CH + c) : z4;
        float4 fz = (m.z >= 0) ? *reinterpret_cast<const float4*>(feat + (size_t)m.z * CH + c) : z4;
        float4 fw = (m.w >= 0) ? *reinterpret_cast<const float4*>(feat + (size_t)m.w * CH + c) : z4;
        *reinterpret_cast<float4*>(outb + (size_t)(c + 0) * NYNX) = make_float4(fx.x, fy.x, fz.x, fw.x);
        *reinterpret_cast<float4*>(outb + (size_t)(c + 1) * NYNX) = make_float4(fx.y, fy.y, fz.y, fw.y);
        *reinterpret_cast<float4*>(outb + (size_t)(c + 2) * NYNX) = make_float4(fx.z, fy.z, fz.z, fw.z);
        *reinterpret_cast<float4*>(outb + (size_t)(c + 3) * NYNX) = make_float4(fx.w, fy.w, fz.w, fw.w);
    }
}

// ---- Fallback path (only if d_ws is too small for the map) ----
__global__ void zero_kernel(float4* __restrict__ out, int n4) {
    int i = blockIdx.x * blockDim.x + threadIdx.x;
    if (i < n4) out[i] = make_float4(0.f, 0.f, 0.f, 0.f);
}

__global__ void direct_scatter_kernel(const float* __restrict__ feat,
                                      const int4* __restrict__ idx,
                                      float* __restrict__ out, int n) {
    int i = blockIdx.x * (blockDim.x / CH) + threadIdx.x / CH;
    int c = threadIdx.x % CH;
    if (i < n) {
        int4 v = idx[i];
        out[(size_t)(v.x * CH + c) * NYNX + v.z * NXD + v.w] = feat[(size_t)i * CH + c];
    }
}

extern "C" void kernel_launch(void* const* d_in, const int* in_sizes, int n_in,
                              void* d_out, int out_size, void* d_ws, size_t ws_size,
                              hipStream_t stream) {
    const float* feat = (const float*)d_in[0];
    const int4*  idx  = (const int4*)d_in[1];
    float*       out  = (float*)d_out;
    const int n = in_sizes[1] / 4;           // number of pillars (192000)

    const size_t map_bytes = (size_t)BATCH * NYNX * sizeof(int);  // 10.24 MB
    if (ws_size >= map_bytes) {
        int* map = (int*)d_ws;
        hipMemsetAsync(map, 0xFF, map_bytes, stream);             // -1 fill
        scatter_map_kernel<<<(n + 255) / 256, 256, 0, stream>>>(idx, map, n);
        dim3 grid((NYNX / 4 + 255) / 256, BATCH);                 // (157, 16)
        gather_kernel<<<grid, 256, 0, stream>>>(feat, map, out);
    } else {
        int n4 = out_size / 4;
        zero_kernel<<<(n4 + 255) / 256, 256, 0, stream>>>((float4*)out, n4);
        direct_scatter_kernel<<<(n + 3) / 4, 256, 0, stream>>>(feat, idx, out, n);
    }
}

// Round 3
// 689.089 us; speedup vs baseline: 1.0319x; 1.0319x over previous
//
#include <hip/hip_runtime.h>

// PointPillars pseudo-image scatter, inverted to a single-pass gather.
// v2.1: native-vector type for nontemporal stores (HIP_vector_type rejected
//       by __builtin_nontemporal_store).
// v2: (1) uint16 per-batch voxel map (5.12 MB, memset 0xFF = sentinel),
//     (2) channel-split gather: preload ALL feature float4s before ANY store
//         (loads and stores share the in-order vmcnt FIFO on CDNA),
//     (3) nontemporal coalesced 16B stores for the 655 MB output.

constexpr int BATCH = 16;
constexpr int CH    = 64;
constexpr int NYD   = 400;
constexpr int NXD   = 400;
constexpr int NYNX  = NYD * NXD;   // 160000 cells per batch
constexpr int NV    = 12000;       // pillars per batch (indices batch-ordered)

typedef float f4 __attribute__((ext_vector_type(4)));

// Phase 1: map[b*NYNX + y*NX + x] = per-batch voxel id (i - b*NV), u16.
// map pre-filled with 0xFFFF via memsetAsync(0xFF).
__global__ void scatter_map_kernel(const int4* __restrict__ idx,
                                   unsigned short* __restrict__ map, int n) {
    int i = blockIdx.x * blockDim.x + threadIdx.x;
    if (i < n) {
        int4 v = idx[i];             // fields: b, z, y, x
        map[v.x * NYNX + v.z * NXD + v.w] = (unsigned short)(i - v.x * NV);
    }
}

// Phase 2: out[b, c, y, x] = live ? feat[(b*NV+j)*CH + c] : 0
// Thread owns 4 x-adjacent cells and 32 channels (blockIdx.z half).
// All 32 f4 loads issue before the 32 f4 stores.
__global__ __launch_bounds__(256)
void gather_kernel(const float* __restrict__ feat,
                   const unsigned short* __restrict__ map,
                   float* __restrict__ out) {
    const int b     = blockIdx.y;
    const int c0    = blockIdx.z * (CH / 2);           // 0 or 32
    const int cell4 = blockIdx.x * blockDim.x + threadIdx.x;
    if (cell4 >= NYNX / 4) return;
    const int yx = cell4 * 4;

    const ushort4 m = *reinterpret_cast<const ushort4*>(map + (size_t)b * NYNX + yx);
    unsigned short js[4] = {m.x, m.y, m.z, m.w};

    const float* featb = feat + ((size_t)b * NV) * CH + c0;
    const f4 z4 = {0.f, 0.f, 0.f, 0.f};

    f4 f[4][8];
    #pragma unroll
    for (int cc = 0; cc < 4; ++cc) {
        if (js[cc] != 0xFFFFu) {
            const f4* src = reinterpret_cast<const f4*>(featb + (size_t)js[cc] * CH);
            #pragma unroll
            for (int k = 0; k < 8; ++k) f[cc][k] = src[k];
        } else {
            #pragma unroll
            for (int k = 0; k < 8; ++k) f[cc][k] = z4;
        }
    }

    float* outb = out + ((size_t)b * CH + c0) * NYNX + yx;
    #pragma unroll
    for (int k = 0; k < 8; ++k) {   // channels c0+4k .. c0+4k+3
        f4 r0 = {f[0][k].x, f[1][k].x, f[2][k].x, f[3][k].x};
        f4 r1 = {f[0][k].y, f[1][k].y, f[2][k].y, f[3][k].y};
        f4 r2 = {f[0][k].z, f[1][k].z, f[2][k].z, f[3][k].z};
        f4 r3 = {f[0][k].w, f[1][k].w, f[2][k].w, f[3][k].w};
        __builtin_nontemporal_store(r0, reinterpret_cast<f4*>(outb + (size_t)(4 * k + 0) * NYNX));
        __builtin_nontemporal_store(r1, reinterpret_cast<f4*>(outb + (size_t)(4 * k + 1) * NYNX));
        __builtin_nontemporal_store(r2, reinterpret_cast<f4*>(outb + (size_t)(4 * k + 2) * NYNX));
        __builtin_nontemporal_store(r3, reinterpret_cast<f4*>(outb + (size_t)(4 * k + 3) * NYNX));
    }
}

// ---- Fallback path (only if d_ws is too small for the map) ----
__global__ void zero_kernel(float4* __restrict__ out, int n4) {
    int i = blockIdx.x * blockDim.x + threadIdx.x;
    if (i < n4) out[i] = make_float4(0.f, 0.f, 0.f, 0.f);
}

__global__ void direct_scatter_kernel(const float* __restrict__ feat,
                                      const int4* __restrict__ idx,
                                      float* __restrict__ out, int n) {
    int i = blockIdx.x * (blockDim.x / CH) + threadIdx.x / CH;
    int c = threadIdx.x % CH;
    if (i < n) {
        int4 v = idx[i];
        out[(size_t)(v.x * CH + c) * NYNX + v.z * NXD + v.w] = feat[(size_t)i * CH + c];
    }
}

extern "C" void kernel_launch(void* const* d_in, const int* in_sizes, int n_in,
                              void* d_out, int out_size, void* d_ws, size_t ws_size,
                              hipStream_t stream) {
    const float* feat = (const float*)d_in[0];
    const int4*  idx  = (const int4*)d_in[1];
    float*       out  = (float*)d_out;
    const int n = in_sizes[1] / 4;           // number of pillars (192000)

    const size_t map_bytes = (size_t)BATCH * NYNX * sizeof(unsigned short);  // 5.12 MB
    if (ws_size >= map_bytes) {
        unsigned short* map = (unsigned short*)d_ws;
        (void)hipMemsetAsync(map, 0xFF, map_bytes, stream);       // 0xFFFF fill
        scatter_map_kernel<<<(n + 255) / 256, 256, 0, stream>>>(idx, map, n);
        dim3 grid((NYNX / 4 + 255) / 256, BATCH, 2);              // (157, 16, 2)
        gather_kernel<<<grid, 256, 0, stream>>>(feat, map, out);
    } else {
        int n4 = out_size / 4;
        zero_kernel<<<(n4 + 255) / 256, 256, 0, stream>>>((float4*)out, n4);
        direct_scatter_kernel<<<(n + 3) / 4, 256, 0, stream>>>(feat, idx, out, n);
    }
}

// Round 4
// 674.432 us; speedup vs baseline: 1.0543x; 1.0217x over previous
//
#include <hip/hip_runtime.h>

// PointPillars pseudo-image scatter, inverted to a single-pass gather.
// v3: channel-slabbed gather (8 slabs of 8 channels) — shrinks per-thread
//     payload from 128 data VGPRs to 8, raising occupancy ~3 -> ~8 waves/SIMD
//     so random feature-load latency (~900 cyc) hides behind other waves'
//     coalesced nontemporal stores. Map (u16, 5.12 MB) re-read per slab is
//     L2/L3-resident and free.

constexpr int BATCH = 16;
constexpr int CH    = 64;
constexpr int NYD   = 400;
constexpr int NXD   = 400;
constexpr int NYNX  = NYD * NXD;   // 160000 cells per batch
constexpr int SLABS = 8;           // 8 channels per slab
constexpr int CPS   = CH / SLABS;  // 8

typedef float f4 __attribute__((ext_vector_type(4)));

// Phase 1: map[b*NYNX + y*NX + x] = per-batch voxel id (i - b*nv), u16.
// map pre-filled with 0xFFFF via memsetAsync(0xFF).
__global__ void scatter_map_kernel(const int4* __restrict__ idx,
                                   unsigned short* __restrict__ map, int n, int nv) {
    int i = blockIdx.x * blockDim.x + threadIdx.x;
    if (i < n) {
        int4 v = idx[i];             // fields: b, z, y, x
        map[v.x * NYNX + v.z * NXD + v.w] = (unsigned short)(i - v.x * nv);
    }
}

// Phase 2: out[b, c, y, x] = live ? feat[(b*nv+j)*CH + c] : 0
// Thread owns 4 x-adjacent cells and 8 channels (blockIdx.z slab).
__global__ __launch_bounds__(256)
void gather_kernel(const float* __restrict__ feat,
                   const unsigned short* __restrict__ map,
                   float* __restrict__ out, int nv) {
    const int b     = blockIdx.y;
    const int c0    = blockIdx.z * CPS;
    const int cell4 = blockIdx.x * blockDim.x + threadIdx.x;
    if (cell4 >= NYNX / 4) return;
    const int yx = cell4 * 4;

    const ushort4 m = *reinterpret_cast<const ushort4*>(map + (size_t)b * NYNX + yx);
    unsigned short js[4] = {m.x, m.y, m.z, m.w};

    const float* featb = feat + ((size_t)b * nv) * CH + c0;
    const f4 z4 = {0.f, 0.f, 0.f, 0.f};

    f4 f[4][CPS / 4];
    #pragma unroll
    for (int cc = 0; cc < 4; ++cc) {
        if (js[cc] != 0xFFFFu) {
            const f4* src = reinterpret_cast<const f4*>(featb + (size_t)js[cc] * CH);
            #pragma unroll
            for (int k = 0; k < CPS / 4; ++k) f[cc][k] = src[k];
        } else {
            #pragma unroll
            for (int k = 0; k < CPS / 4; ++k) f[cc][k] = z4;
        }
    }

    float* outb = out + ((size_t)b * CH + c0) * NYNX + yx;
    #pragma unroll
    for (int k = 0; k < CPS / 4; ++k) {   // channels c0+4k .. c0+4k+3
        f4 r0 = {f[0][k].x, f[1][k].x, f[2][k].x, f[3][k].x};
        f4 r1 = {f[0][k].y, f[1][k].y, f[2][k].y, f[3][k].y};
        f4 r2 = {f[0][k].z, f[1][k].z, f[2][k].z, f[3][k].z};
        f4 r3 = {f[0][k].w, f[1][k].w, f[2][k].w, f[3][k].w};
        __builtin_nontemporal_store(r0, reinterpret_cast<f4*>(outb + (size_t)(4 * k + 0) * NYNX));
        __builtin_nontemporal_store(r1, reinterpret_cast<f4*>(outb + (size_t)(4 * k + 1) * NYNX));
        __builtin_nontemporal_store(r2, reinterpret_cast<f4*>(outb + (size_t)(4 * k + 2) * NYNX));
        __builtin_nontemporal_store(r3, reinterpret_cast<f4*>(outb + (size_t)(4 * k + 3) * NYNX));
    }
}

// ---- Fallback path (only if d_ws is too small for the map) ----
__global__ void zero_kernel(float4* __restrict__ out, int n4) {
    int i = blockIdx.x * blockDim.x + threadIdx.x;
    if (i < n4) out[i] = make_float4(0.f, 0.f, 0.f, 0.f);
}

__global__ void direct_scatter_kernel(const float* __restrict__ feat,
                                      const int4* __restrict__ idx,
                                      float* __restrict__ out, int n) {
    int i = blockIdx.x * (blockDim.x / CH) + threadIdx.x / CH;
    int c = threadIdx.x % CH;
    if (i < n) {
        int4 v = idx[i];
        out[(size_t)(v.x * CH + c) * NYNX + v.z * NXD + v.w] = feat[(size_t)i * CH + c];
    }
}

extern "C" void kernel_launch(void* const* d_in, const int* in_sizes, int n_in,
                              void* d_out, int out_size, void* d_ws, size_t ws_size,
                              hipStream_t stream) {
    const float* feat = (const float*)d_in[0];
    const int4*  idx  = (const int4*)d_in[1];
    float*       out  = (float*)d_out;
    const int n  = in_sizes[1] / 4;          // number of pillars (192000)
    const int nv = n / BATCH;                // pillars per batch (12000)

    const size_t map_bytes = (size_t)BATCH * NYNX * sizeof(unsigned short);  // 5.12 MB
    if (ws_size >= map_bytes && nv < 0xFFFF) {
        unsigned short* map = (unsigned short*)d_ws;
        (void)hipMemsetAsync(map, 0xFF, map_bytes, stream);       // 0xFFFF fill
        scatter_map_kernel<<<(n + 255) / 256, 256, 0, stream>>>(idx, map, n, nv);
        dim3 grid((NYNX / 4 + 255) / 256, BATCH, SLABS);          // (157, 16, 8)
        gather_kernel<<<grid, 256, 0, stream>>>(feat, map, out, nv);
    } else {
        int n4 = out_size / 4;
        zero_kernel<<<(n4 + 255) / 256, 256, 0, stream>>>((float4*)out, n4);
        direct_scatter_kernel<<<(n + 3) / 4, 256, 0, stream>>>(feat, idx, out, n);
    }
}

// Round 5
// 673.822 us; speedup vs baseline: 1.0553x; 1.0009x over previous
//
#include <hip/hip_runtime.h>

// PointPillars pseudo-image scatter, inverted to a single-pass gather.
// v4: two 4-cell groups per thread (halves wave count; all loads before all
//     stores; stores stay fully-dense 1024 B per wave-instruction).
// v3: 8 channel slabs -> 8 data VGPRs/group, ~5-8 waves/SIMD.
// v2: u16 per-batch voxel map (5.12 MB, memset 0xFF sentinel); nontemporal
//     coalesced 16 B stores for the 655 MB output (written exactly once).

constexpr int BATCH = 16;
constexpr int CH    = 64;
constexpr int NYD   = 400;
constexpr int NXD   = 400;
constexpr int NYNX  = NYD * NXD;   // 160000 cells per batch
constexpr int SLABS = 8;           // 8 channels per slab
constexpr int CPS   = CH / SLABS;  // 8
constexpr int TILE  = 2048;        // cells per block (256 thr * 4 cells * 2 groups)

typedef float f4 __attribute__((ext_vector_type(4)));

// Phase 1: map[b*NYNX + y*NX + x] = per-batch voxel id (i - b*nv), u16.
// map pre-filled with 0xFFFF via memsetAsync(0xFF).
__global__ void scatter_map_kernel(const int4* __restrict__ idx,
                                   unsigned short* __restrict__ map, int n, int nv) {
    int i = blockIdx.x * blockDim.x + threadIdx.x;
    if (i < n) {
        int4 v = idx[i];             // fields: b, z, y, x
        map[v.x * NYNX + v.z * NXD + v.w] = (unsigned short)(i - v.x * nv);
    }
}

// Phase 2: out[b, c, y, x] = live ? feat[(b*nv+j)*CH + c] : 0
// Thread owns 2 groups of 4 x-adjacent cells (1024 apart) and 8 channels.
__global__ __launch_bounds__(256)
void gather_kernel(const float* __restrict__ feat,
                   const unsigned short* __restrict__ map,
                   float* __restrict__ out, int nv) {
    const int b    = blockIdx.y;
    const int c0   = blockIdx.z * CPS;
    const int base = blockIdx.x * TILE + threadIdx.x * 4;

    const unsigned short* mapb  = map + (size_t)b * NYNX;
    const float*          featb = feat + ((size_t)b * nv) * CH + c0;
    float*                outb  = out + ((size_t)b * CH + c0) * NYNX;
    const f4 z4 = {0.f, 0.f, 0.f, 0.f};

    // ---- load phase (no stores issued yet) ----
    bool gv[2];
    unsigned short js[2][4];
    f4 f[2][4][2];
    #pragma unroll
    for (int g = 0; g < 2; ++g) {
        const int yx = base + g * 1024;
        gv[g] = (yx < NYNX);
        ushort4 m = gv[g] ? *reinterpret_cast<const ushort4*>(mapb + yx)
                          : make_ushort4(0xFFFFu, 0xFFFFu, 0xFFFFu, 0xFFFFu);
        js[g][0] = m.x; js[g][1] = m.y; js[g][2] = m.z; js[g][3] = m.w;
        #pragma unroll
        for (int cc = 0; cc < 4; ++cc) {
            if (js[g][cc] != 0xFFFFu) {
                const f4* src = reinterpret_cast<const f4*>(featb + (size_t)js[g][cc] * CH);
                f[g][cc][0] = src[0];
                f[g][cc][1] = src[1];
            } else {
                f[g][cc][0] = z4;
                f[g][cc][1] = z4;
            }
        }
    }

    // ---- store phase: 16 dense nontemporal 16 B stores ----
    #pragma unroll
    for (int g = 0; g < 2; ++g) {
        if (!gv[g]) continue;
        const int yx = base + g * 1024;
        #pragma unroll
        for (int k = 0; k < 2; ++k) {   // channels c0+4k .. c0+4k+3
            f4 r0 = {f[g][0][k].x, f[g][1][k].x, f[g][2][k].x, f[g][3][k].x};
            f4 r1 = {f[g][0][k].y, f[g][1][k].y, f[g][2][k].y, f[g][3][k].y};
            f4 r2 = {f[g][0][k].z, f[g][1][k].z, f[g][2][k].z, f[g][3][k].z};
            f4 r3 = {f[g][0][k].w, f[g][1][k].w, f[g][2][k].w, f[g][3][k].w};
            __builtin_nontemporal_store(r0, reinterpret_cast<f4*>(outb + (size_t)(4 * k + 0) * NYNX + yx));
            __builtin_nontemporal_store(r1, reinterpret_cast<f4*>(outb + (size_t)(4 * k + 1) * NYNX + yx));
            __builtin_nontemporal_store(r2, reinterpret_cast<f4*>(outb + (size_t)(4 * k + 2) * NYNX + yx));
            __builtin_nontemporal_store(r3, reinterpret_cast<f4*>(outb + (size_t)(4 * k + 3) * NYNX + yx));
        }
    }
}

// ---- Fallback path (only if d_ws is too small for the map) ----
__global__ void zero_kernel(float4* __restrict__ out, int n4) {
    int i = blockIdx.x * blockDim.x + threadIdx.x;
    if (i < n4) out[i] = make_float4(0.f, 0.f, 0.f, 0.f);
}

__global__ void direct_scatter_kernel(const float* __restrict__ feat,
                                      const int4* __restrict__ idx,
                                      float* __restrict__ out, int n) {
    int i = blockIdx.x * (blockDim.x / CH) + threadIdx.x / CH;
    int c = threadIdx.x % CH;
    if (i < n) {
        int4 v = idx[i];
        out[(size_t)(v.x * CH + c) * NYNX + v.z * NXD + v.w] = feat[(size_t)i * CH + c];
    }
}

extern "C" void kernel_launch(void* const* d_in, const int* in_sizes, int n_in,
                              void* d_out, int out_size, void* d_ws, size_t ws_size,
                              hipStream_t stream) {
    const float* feat = (const float*)d_in[0];
    const int4*  idx  = (const int4*)d_in[1];
    float*       out  = (float*)d_out;
    const int n  = in_sizes[1] / 4;          // number of pillars (192000)
    const int nv = n / BATCH;                // pillars per batch (12000)

    const size_t map_bytes = (size_t)BATCH * NYNX * sizeof(unsigned short);  // 5.12 MB
    if (ws_size >= map_bytes && nv < 0xFFFF) {
        unsigned short* map = (unsigned short*)d_ws;
        (void)hipMemsetAsync(map, 0xFF, map_bytes, stream);       // 0xFFFF fill
        scatter_map_kernel<<<(n + 255) / 256, 256, 0, stream>>>(idx, map, n, nv);
        dim3 grid((NYNX + TILE - 1) / TILE, BATCH, SLABS);        // (79, 16, 8)
        gather_kernel<<<grid, 256, 0, stream>>>(feat, map, out, nv);
    } else {
        int n4 = out_size / 4;
        zero_kernel<<<(n4 + 255) / 256, 256, 0, stream>>>((float4*)out, n4);
        direct_scatter_kernel<<<(n + 3) / 4, 256, 0, stream>>>(feat, idx, out, n);
    }
}